// Round 1
// baseline (193.900 us; speedup 1.0000x reference)
//
#include <hip/hip_runtime.h>
#include <hip/hip_cooperative_groups.h>
#include <math.h>

namespace cg = cooperative_groups;

#define N_SPK 512
#define N_UTT 32
#define DIM   512
#define EPSN  1e-8f
#define NBLK  256   // fused kernel: 2 speakers per block
#define NTHR  1024  // 16 waves

typedef __attribute__((ext_vector_type(8))) short  short8;  // 8 bf16 = 4 VGPR
typedef __attribute__((ext_vector_type(4))) float  f32x4;   // MFMA C/D

// fp32 -> bf16 round-to-nearest-even
__device__ inline unsigned short f2bf(float x) {
  unsigned int u = __builtin_bit_cast(unsigned int, x);
  unsigned int r = (u + 0x7fffu + ((u >> 16) & 1u)) >> 16;
  return (unsigned short)r;
}

// ws layout: [0, 512KB) = cnk (bf16, K-chunked); [512KB, +2KB) = block partials
#define CNK_ELEMS (N_SPK * DIM)

// ============================================================================
// Fused cooperative kernel: 256 blocks x 1024 threads (16 waves), 1 block/CU.
// Block b owns speakers j0=2b, j1=2b+1 (M=64 output rows).
// Phase 1: read emb ONCE (128KB/block), row-normalize -> E (LDS bf16,
//          XOR-swizzled), fp32 centroid sums -> normalized bf16 cnk (global,
//          K-chunked: cnk[(kc*N_SPK+c)*32 + (k&31)]).
// grid.sync()
// Phase 2: MFMA GEMM 64x512x512; B read straight from cnk (L2-resident;
//          256 blocks -> 134MB L2 traffic, half of the 512-block layout).
//          Fused w*sim+b, LSE + diag; one partial per block.
// ============================================================================
__global__ __launch_bounds__(NTHR) void ge2e_fused(
    const float* __restrict__ emb, unsigned short* __restrict__ cnk,
    const float* __restrict__ wp, const float* __restrict__ bp,
    float* __restrict__ partials) {
  __shared__ __align__(16) unsigned short E[64 * DIM];  // 64 KB
  __shared__ __align__(16) float part[14][DIM];         // 28 KB centroid partials
  __shared__ float red[16][64][2];                      // 8 KB (m, s) per wave/row
  __shared__ float dred[16];

  int b = blockIdx.x;
  int t = threadIdx.x;
  int lane = t & 63, wid = t >> 6;
  int n15 = lane & 15, quad = lane >> 4;
  int sp = wid >> 3, ws8 = wid & 7;  // wave's speaker half + index within it
  int j = 2 * b + sp;

  // ---- phase 1: stage 4 rows/wave, normalize -> E, centroid partials ----
  float4 v0[4], v1[4];
  const float* base = emb + ((size_t)j * N_UTT + ws8 * 4) * DIM + lane * 8;
#pragma unroll
  for (int r4 = 0; r4 < 4; ++r4) {  // issue all 8 loads first (MLP)
    v0[r4] = *(const float4*)(base + r4 * DIM);
    v1[r4] = *(const float4*)(base + r4 * DIM + 4);
  }
  float cen[8] = {0.f, 0.f, 0.f, 0.f, 0.f, 0.f, 0.f, 0.f};
#pragma unroll
  for (int r4 = 0; r4 < 4; ++r4) {
    cen[0] += v0[r4].x; cen[1] += v0[r4].y; cen[2] += v0[r4].z; cen[3] += v0[r4].w;
    cen[4] += v1[r4].x; cen[5] += v1[r4].y; cen[6] += v1[r4].z; cen[7] += v1[r4].w;
    float ss = v0[r4].x * v0[r4].x + v0[r4].y * v0[r4].y +
               v0[r4].z * v0[r4].z + v0[r4].w * v0[r4].w +
               v1[r4].x * v1[r4].x + v1[r4].y * v1[r4].y +
               v1[r4].z * v1[r4].z + v1[r4].w * v1[r4].w;
#pragma unroll
    for (int off = 32; off > 0; off >>= 1) ss += __shfl_xor(ss, off, 64);
    float inv = 1.f / fmaxf(sqrtf(ss), EPSN);
    short8 pk;
    pk[0] = (short)f2bf(v0[r4].x * inv); pk[1] = (short)f2bf(v0[r4].y * inv);
    pk[2] = (short)f2bf(v0[r4].z * inv); pk[3] = (short)f2bf(v0[r4].w * inv);
    pk[4] = (short)f2bf(v1[r4].x * inv); pk[5] = (short)f2bf(v1[r4].y * inv);
    pk[6] = (short)f2bf(v1[r4].z * inv); pk[7] = (short)f2bf(v1[r4].w * inv);
    int R = sp * 32 + ws8 * 4 + r4;  // block row 0..63
    int sw = lane ^ (R & 7);
    *(short8*)&E[R * DIM + sw * 8] = pk;
  }
  if (ws8 != 0) {  // 7 partial waves per speaker dump to LDS
    float* p = &part[sp * 7 + ws8 - 1][lane * 8];
    *(float4*)p       = (float4){cen[0], cen[1], cen[2], cen[3]};
    *(float4*)(p + 4) = (float4){cen[4], cen[5], cen[6], cen[7]};
  }
  __syncthreads();
  if (ws8 == 0) {  // waves 0 and 8 finish their speaker's centroid
#pragma unroll
    for (int i = 0; i < 7; ++i) {
      const float* p = &part[sp * 7 + i][lane * 8];
      float4 a = *(const float4*)p, c = *(const float4*)(p + 4);
      cen[0] += a.x; cen[1] += a.y; cen[2] += a.z; cen[3] += a.w;
      cen[4] += c.x; cen[5] += c.y; cen[6] += c.z; cen[7] += c.w;
    }
    float ss = 0.f;
#pragma unroll
    for (int k = 0; k < 8; ++k) {
      cen[k] *= (1.f / N_UTT);
      ss += cen[k] * cen[k];
    }
#pragma unroll
    for (int off = 32; off > 0; off >>= 1) ss += __shfl_xor(ss, off, 64);
    float inv = 1.f / fmaxf(sqrtf(ss), EPSN);
    int kc = lane >> 2, ko = (lane & 3) * 8;  // dims lane*8..+7 in k-chunks
    short8 pk;
#pragma unroll
    for (int k = 0; k < 8; ++k) pk[k] = (short)f2bf(cen[k] * inv);
    *(short8*)(cnk + ((size_t)kc * N_SPK + j) * 32 + ko) = pk;
  }
  __threadfence();          // device-scope release of cnk stores
  cg::this_grid().sync();   // all 512 centroids visible device-wide

  // ---- phase 2: GEMM. wave wid: cols wid*32..+31, rows 0..63 ----
  f32x4 acc[4][2];
#pragma unroll
  for (int mt = 0; mt < 4; ++mt)
#pragma unroll
    for (int nt = 0; nt < 2; ++nt) acc[mt][nt] = (f32x4){0.f, 0.f, 0.f, 0.f};

#pragma unroll 4
  for (int ks = 0; ks < 16; ++ks) {
    short8 bfr[2];
#pragma unroll
    for (int nt = 0; nt < 2; ++nt) {
      int c = wid * 32 + nt * 16 + n15;  // B[n][k]: lane=col, quad picks 8 k's
      bfr[nt] = *(const short8*)(cnk + ((size_t)ks * N_SPK + c) * 32 + quad * 8);
    }
    short8 afr[4];
#pragma unroll
    for (int mt = 0; mt < 4; ++mt) {
      int r = mt * 16 + n15;
      int sw = (ks * 4 + quad) ^ (r & 7);
      afr[mt] = *(const short8*)&E[r * DIM + sw * 8];
    }
#pragma unroll
    for (int mt = 0; mt < 4; ++mt)
#pragma unroll
      for (int nt = 0; nt < 2; ++nt)
        acc[mt][nt] = __builtin_amdgcn_mfma_f32_16x16x32_bf16(
            afr[mt], bfr[nt], acc[mt][nt], 0, 0, 0);
  }

  // ---- epilogue: logits = w*sim+b, fused LSE + diag ----
  float w = *wp, bb = *bp;
  float dsum = 0.f;
#pragma unroll
  for (int mt = 0; mt < 4; ++mt)
#pragma unroll
    for (int nt = 0; nt < 2; ++nt) {
      int c = wid * 32 + nt * 16 + n15;
      bool isdiag = (c == 2 * b + (mt >> 1));  // rows mt*16.. are speaker mt>>1
#pragma unroll
      for (int rg = 0; rg < 4; ++rg) {
        float v = fmaf(w, acc[mt][nt][rg], bb);
        acc[mt][nt][rg] = v;
        if (isdiag) dsum += v;
      }
    }

#pragma unroll
  for (int mt = 0; mt < 4; ++mt)
#pragma unroll
    for (int rg = 0; rg < 4; ++rg) {
      float m = fmaxf(acc[mt][0][rg], acc[mt][1][rg]);
#pragma unroll
      for (int off = 1; off < 16; off <<= 1) m = fmaxf(m, __shfl_xor(m, off, 64));
      float s = __expf(acc[mt][0][rg] - m) + __expf(acc[mt][1][rg] - m);
#pragma unroll
      for (int off = 1; off < 16; off <<= 1) s += __shfl_xor(s, off, 64);
      if (n15 == 0) {
        int r = mt * 16 + quad * 4 + rg;  // C/D: row = quad*4+reg within tile
        red[wid][r][0] = m;
        red[wid][r][1] = s;
      }
    }
#pragma unroll
  for (int off = 32; off > 0; off >>= 1) dsum += __shfl_xor(dsum, off, 64);
  if (lane == 0) dred[wid] = dsum;
  __syncthreads();

  if (t < 64) {  // wave 0 combines 16 wave-partials for its row t
    float M = -INFINITY;
#pragma unroll
    for (int ww = 0; ww < 16; ++ww) M = fmaxf(M, red[ww][t][0]);
    float S = 0.f;
#pragma unroll
    for (int ww = 0; ww < 16; ++ww) S += red[ww][t][1] * __expf(red[ww][t][0] - M);
    float lse = M + __logf(S);
#pragma unroll
    for (int off = 32; off > 0; off >>= 1) lse += __shfl_xor(lse, off, 64);
    if (t == 0) {
      float d = 0.f;
#pragma unroll
      for (int ww = 0; ww < 16; ++ww) d += dred[ww];
      partials[b] = lse - d;
    }
  }
}

// Reduce n per-block partials -> loss scalar (n = 256 fused / 512 fallback).
__global__ __launch_bounds__(512) void finalize_kernel(
    const float* __restrict__ partials, float* __restrict__ out, int n) {
  int t = threadIdx.x;
  float v = (t < n) ? partials[t] : 0.f;
#pragma unroll
  for (int off = 32; off > 0; off >>= 1) v += __shfl_xor(v, off, 64);
  __shared__ float r[8];
  if ((t & 63) == 0) r[t >> 6] = v;
  __syncthreads();
  if (t == 0) {
    float s = r[0] + r[1] + r[2] + r[3] + r[4] + r[5] + r[6] + r[7];
    out[0] = s * (1.f / (N_SPK * N_UTT));
  }
}

// ============================================================================
// Fallback path (previous verified 3-kernel version) — used only if the
// cooperative launch is rejected (e.g. graph-capture limitation).
// ============================================================================
__global__ __launch_bounds__(256) void centroid_kernel(
    const float* __restrict__ emb, unsigned short* __restrict__ cnk) {
  int j = blockIdx.x, t = threadIdx.x;
  int c4 = t & 127, half = t >> 7;
  const float4* base = (const float4*)(emb + (size_t)j * N_UTT * DIM);
  float4 s = {0.f, 0.f, 0.f, 0.f};
#pragma unroll
  for (int u = 0; u < 16; ++u) {
    float4 v = base[(half + 2 * u) * 128 + c4];
    s.x += v.x; s.y += v.y; s.z += v.z; s.w += v.w;
  }
  __shared__ float4 comb[128];
  if (half) comb[c4] = s;
  __syncthreads();
  float4 m = {0.f, 0.f, 0.f, 0.f};
  float ss = 0.f;
  if (!half) {
    float4 o = comb[c4];
    m.x = (s.x + o.x) * (1.f / N_UTT);
    m.y = (s.y + o.y) * (1.f / N_UTT);
    m.z = (s.z + o.z) * (1.f / N_UTT);
    m.w = (s.w + o.w) * (1.f / N_UTT);
    ss = m.x * m.x + m.y * m.y + m.z * m.z + m.w * m.w;
  }
#pragma unroll
  for (int off = 32; off > 0; off >>= 1) ss += __shfl_xor(ss, off, 64);
  __shared__ float red[4];
  if ((t & 63) == 0) red[t >> 6] = ss;
  __syncthreads();
  float total = red[0] + red[1] + red[2] + red[3];
  float inv = 1.f / fmaxf(sqrtf(total), EPSN);
  if (!half) {
    int d0 = c4 * 4;
    int kc = d0 >> 5;
    unsigned short* p = cnk + ((size_t)kc * N_SPK + j) * 32 + (d0 & 31);
    p[0] = f2bf(m.x * inv); p[1] = f2bf(m.y * inv);
    p[2] = f2bf(m.z * inv); p[3] = f2bf(m.w * inv);
  }
}

__global__ __launch_bounds__(512, 4) void ge2e_kernel(
    const float* __restrict__ emb, const unsigned short* __restrict__ cnk,
    const float* __restrict__ wp, const float* __restrict__ bp,
    float* __restrict__ partials) {
  __shared__ __align__(16) unsigned short E[N_UTT * DIM];
  __shared__ float red[8][N_UTT][2];
  __shared__ float dred[8];

  int j = blockIdx.x;
  int t = threadIdx.x;
  int lane = t & 63, wid = t >> 6;
  int n15 = lane & 15, quad = lane >> 4;

#pragma unroll
  for (int r8 = 0; r8 < 4; ++r8) {
    int r = wid * 4 + r8;
    const float* rp = emb + ((size_t)j * N_UTT + r) * DIM + lane * 8;
    float4 v0 = *(const float4*)rp;
    float4 v1 = *(const float4*)(rp + 4);
    float ss = v0.x * v0.x + v0.y * v0.y + v0.z * v0.z + v0.w * v0.w +
               v1.x * v1.x + v1.y * v1.y + v1.z * v1.z + v1.w * v1.w;
#pragma unroll
    for (int off = 32; off > 0; off >>= 1) ss += __shfl_xor(ss, off, 64);
    float inv = 1.f / fmaxf(sqrtf(ss), EPSN);
    short8 pk;
    pk[0] = (short)f2bf(v0.x * inv); pk[1] = (short)f2bf(v0.y * inv);
    pk[2] = (short)f2bf(v0.z * inv); pk[3] = (short)f2bf(v0.w * inv);
    pk[4] = (short)f2bf(v1.x * inv); pk[5] = (short)f2bf(v1.y * inv);
    pk[6] = (short)f2bf(v1.z * inv); pk[7] = (short)f2bf(v1.w * inv);
    int sw = lane ^ (r & 7);
    *(short8*)&E[r * DIM + sw * 8] = pk;
  }
  __syncthreads();

  f32x4 acc[2][4];
#pragma unroll
  for (int mt = 0; mt < 2; ++mt)
#pragma unroll
    for (int nt = 0; nt < 4; ++nt) acc[mt][nt] = (f32x4){0.f, 0.f, 0.f, 0.f};

  for (int ks = 0; ks < 16; ++ks) {
    short8 bf[4];
#pragma unroll
    for (int nt = 0; nt < 4; ++nt) {
      int c = wid * 64 + nt * 16 + n15;
      bf[nt] = *(const short8*)(cnk + ((size_t)ks * N_SPK + c) * 32 + quad * 8);
    }
    short8 af[2];
#pragma unroll
    for (int mt = 0; mt < 2; ++mt) {
      int r = mt * 16 + n15;
      int sw = (ks * 4 + quad) ^ (r & 7);
      af[mt] = *(const short8*)&E[r * DIM + sw * 8];
    }
#pragma unroll
    for (int mt = 0; mt < 2; ++mt)
#pragma unroll
      for (int nt = 0; nt < 4; ++nt)
        acc[mt][nt] = __builtin_amdgcn_mfma_f32_16x16x32_bf16(
            af[mt], bf[nt], acc[mt][nt], 0, 0, 0);
  }

  float w = *wp, bb = *bp;
  float dsum = 0.f;
#pragma unroll
  for (int mt = 0; mt < 2; ++mt)
#pragma unroll
    for (int nt = 0; nt < 4; ++nt) {
      int c = wid * 64 + nt * 16 + n15;
      bool isdiag = (c == j);
#pragma unroll
      for (int rg = 0; rg < 4; ++rg) {
        float v = fmaf(w, acc[mt][nt][rg], bb);
        acc[mt][nt][rg] = v;
        if (isdiag) dsum += v;
      }
    }

#pragma unroll
  for (int mt = 0; mt < 2; ++mt)
#pragma unroll
    for (int rg = 0; rg < 4; ++rg) {
      float m = -INFINITY;
#pragma unroll
      for (int nt = 0; nt < 4; ++nt) m = fmaxf(m, acc[mt][nt][rg]);
#pragma unroll
      for (int off = 1; off < 16; off <<= 1) m = fmaxf(m, __shfl_xor(m, off, 64));
      float s = 0.f;
#pragma unroll
      for (int nt = 0; nt < 4; ++nt) s += __expf(acc[mt][nt][rg] - m);
#pragma unroll
      for (int off = 1; off < 16; off <<= 1) s += __shfl_xor(s, off, 64);
      if (n15 == 0) {
        int r = mt * 16 + quad * 4 + rg;
        red[wid][r][0] = m;
        red[wid][r][1] = s;
      }
    }
#pragma unroll
  for (int off = 32; off > 0; off >>= 1) dsum += __shfl_xor(dsum, off, 64);
  if (lane == 0) dred[wid] = dsum;
  __syncthreads();

  if (t < 32) {
    float M = -INFINITY;
#pragma unroll
    for (int ww = 0; ww < 8; ++ww) M = fmaxf(M, red[ww][t][0]);
    float S = 0.f;
#pragma unroll
    for (int ww = 0; ww < 8; ++ww) S += red[ww][t][1] * __expf(red[ww][t][0] - M);
    float lse = M + __logf(S);
#pragma unroll
    for (int off = 16; off > 0; off >>= 1) lse += __shfl_xor(lse, off, 64);
    if (t == 0) {
      float d = dred[0] + dred[1] + dred[2] + dred[3] +
                dred[4] + dred[5] + dred[6] + dred[7];
      partials[j] = lse - d;
    }
  }
}

extern "C" void kernel_launch(void* const* d_in, const int* in_sizes, int n_in,
                              void* d_out, int out_size, void* d_ws, size_t ws_size,
                              hipStream_t stream) {
  const float* emb = (const float*)d_in[0];
  const float* wp  = (const float*)d_in[1];
  const float* bp  = (const float*)d_in[2];
  float* out = (float*)d_out;
  unsigned short* cnk = (unsigned short*)d_ws;                       // 512 KB
  float* partials = (float*)((char*)d_ws + (size_t)CNK_ELEMS * 2);   // 2 KB

  void* args[] = {(void*)&emb, (void*)&cnk, (void*)&wp, (void*)&bp,
                  (void*)&partials};
  hipError_t err = hipLaunchCooperativeKernel(
      (const void*)ge2e_fused, dim3(NBLK), dim3(NTHR), args, 0, stream);
  if (err == hipSuccess) {
    finalize_kernel<<<1, 512, 0, stream>>>(partials, out, NBLK);
  } else {
    // cooperative launch unavailable (e.g. capture limitation): 3-kernel path
    centroid_kernel<<<N_SPK, 256, 0, stream>>>(emb, cnk);
    ge2e_kernel<<<N_SPK, 512, 0, stream>>>(emb, cnk, wp, bp, partials);
    finalize_kernel<<<1, 512, 0, stream>>>(partials, out, N_SPK);
  }
}

// Round 2
// 103.622 us; speedup vs baseline: 1.8712x; 1.8712x over previous
//
#include <hip/hip_runtime.h>
#include <math.h>

#define N_SPK 512
#define N_UTT 32
#define DIM   512
#define EPSN  1e-8f

typedef __attribute__((ext_vector_type(8))) short  short8;  // 8 bf16 = 4 VGPR
typedef __attribute__((ext_vector_type(4))) float  f32x4;   // MFMA C/D

// fp32 -> bf16 round-to-nearest-even
__device__ inline unsigned short f2bf(float x) {
  unsigned int u = __builtin_bit_cast(unsigned int, x);
  unsigned int r = (u + 0x7fffu + ((u >> 16) & 1u)) >> 16;
  return (unsigned short)r;
}

// ws layout: [0, 512KB) = cnk (bf16, K-chunked); then partials (2KB); then cnt
#define CNK_ELEMS (N_SPK * DIM)

// Kernel 1: centroid (mean over U) + L2-normalize (fp32) -> bf16, stored
// K-CHUNKED: cnk[(kc*N_SPK + c)*32 + (k&31)], kc = k/32 -> GEMM B-frag loads
// land in a contiguous 1KB run per instruction (full cache-line use).
// Also re-zeroes the ticket counter used by ge2e's fused finalize (stream
// order guarantees this lands after the harness poison, before ge2e).
__global__ __launch_bounds__(256) void centroid_kernel(
    const float* __restrict__ emb, unsigned short* __restrict__ cnk,
    unsigned int* __restrict__ cnt) {
  if (blockIdx.x == 0 && threadIdx.x == 0)
    __hip_atomic_store(cnt, 0u, __ATOMIC_RELAXED, __HIP_MEMORY_SCOPE_AGENT);
  int j = blockIdx.x, t = threadIdx.x;
  int c4 = t & 127, half = t >> 7;  // c4: which float4 of the row (128/row)
  const float4* base = (const float4*)(emb + (size_t)j * N_UTT * DIM);
  float4 s = {0.f, 0.f, 0.f, 0.f};
#pragma unroll
  for (int u = 0; u < 16; ++u) {
    float4 v = base[(half + 2 * u) * 128 + c4];
    s.x += v.x; s.y += v.y; s.z += v.z; s.w += v.w;
  }
  __shared__ float4 comb[128];
  if (half) comb[c4] = s;
  __syncthreads();
  float4 m = {0.f, 0.f, 0.f, 0.f};
  float ss = 0.f;
  if (!half) {
    float4 o = comb[c4];
    m.x = (s.x + o.x) * (1.f / N_UTT);
    m.y = (s.y + o.y) * (1.f / N_UTT);
    m.z = (s.z + o.z) * (1.f / N_UTT);
    m.w = (s.w + o.w) * (1.f / N_UTT);
    ss = m.x * m.x + m.y * m.y + m.z * m.z + m.w * m.w;
  }
#pragma unroll
  for (int off = 32; off > 0; off >>= 1) ss += __shfl_xor(ss, off, 64);
  __shared__ float red[4];
  if ((t & 63) == 0) red[t >> 6] = ss;
  __syncthreads();
  float total = red[0] + red[1] + red[2] + red[3];
  float inv = 1.f / fmaxf(sqrtf(total), EPSN);
  if (!half) {
    int d0 = c4 * 4;          // first of this thread's 4 dims
    int kc = d0 >> 5;         // k-chunk
    unsigned short* p = cnk + ((size_t)kc * N_SPK + j) * 32 + (d0 & 31);
    p[0] = f2bf(m.x * inv); p[1] = f2bf(m.y * inv);
    p[2] = f2bf(m.z * inv); p[3] = f2bf(m.w * inv);
  }
}

// Kernel 2: one block per speaker j, 512 threads (8 waves). E tile (32x512
// bf16, 32KB) XOR-swizzled; B-frags straight from contiguous cnk. Per-block
// loss partial stored agent-scope (bypasses the XCD-private L2 so the last
// block can read it without fences); the LAST block to finish runs the
// finalize reduction in exactly finalize_kernel's order (bit-identical).
__global__ __launch_bounds__(512, 4) void ge2e_kernel(
    const float* __restrict__ emb, const unsigned short* __restrict__ cnk,
    const float* __restrict__ wp, const float* __restrict__ bp,
    float* __restrict__ partials, unsigned int* __restrict__ cnt,
    float* __restrict__ out) {
  __shared__ __align__(16) unsigned short E[N_UTT * DIM];  // 32 KB
  __shared__ float red[8][N_UTT][2];                       // 2 KB (m, s)
  __shared__ float dred[8];
  __shared__ int lastflag;

  int j = blockIdx.x;
  int t = threadIdx.x;
  int lane = t & 63, wid = t >> 6;
  int n15 = lane & 15, quad = lane >> 4;

  // ---- stage + fp32 normalize + bf16 pack; wave wid owns rows wid*4.. ----
#pragma unroll
  for (int r8 = 0; r8 < 4; ++r8) {
    int r = wid * 4 + r8;
    const float* rp = emb + ((size_t)j * N_UTT + r) * DIM + lane * 8;
    float4 v0 = *(const float4*)rp;
    float4 v1 = *(const float4*)(rp + 4);
    float ss = v0.x * v0.x + v0.y * v0.y + v0.z * v0.z + v0.w * v0.w +
               v1.x * v1.x + v1.y * v1.y + v1.z * v1.z + v1.w * v1.w;
#pragma unroll
    for (int off = 32; off > 0; off >>= 1) ss += __shfl_xor(ss, off, 64);
    float inv = 1.f / fmaxf(sqrtf(ss), EPSN);
    short8 pk;
    pk[0] = (short)f2bf(v0.x * inv); pk[1] = (short)f2bf(v0.y * inv);
    pk[2] = (short)f2bf(v0.z * inv); pk[3] = (short)f2bf(v0.w * inv);
    pk[4] = (short)f2bf(v1.x * inv); pk[5] = (short)f2bf(v1.y * inv);
    pk[6] = (short)f2bf(v1.z * inv); pk[7] = (short)f2bf(v1.w * inv);
    int sw = lane ^ (r & 7);
    *(short8*)&E[r * DIM + sw * 8] = pk;
  }
  __syncthreads();

  // ---- MFMA GEMM: wave wid computes rows 0..31 x cols wid*64..+63 ----
  f32x4 acc[2][4];
#pragma unroll
  for (int mt = 0; mt < 2; ++mt)
#pragma unroll
    for (int nt = 0; nt < 4; ++nt) acc[mt][nt] = (f32x4){0.f, 0.f, 0.f, 0.f};

  for (int ks = 0; ks < 16; ++ks) {
    short8 b[4];
#pragma unroll
    for (int nt = 0; nt < 4; ++nt) {
      int c = wid * 64 + nt * 16 + n15;  // B[n][k]: lane=col, quad*8 k's
      b[nt] = *(const short8*)(cnk + ((size_t)ks * N_SPK + c) * 32 + quad * 8);
    }
    short8 a[2];
#pragma unroll
    for (int mt = 0; mt < 2; ++mt) {
      int r = mt * 16 + n15;
      int sw = (ks * 4 + quad) ^ (r & 7);
      a[mt] = *(const short8*)&E[r * DIM + sw * 8];
    }
#pragma unroll
    for (int mt = 0; mt < 2; ++mt)
#pragma unroll
      for (int nt = 0; nt < 4; ++nt)
        acc[mt][nt] = __builtin_amdgcn_mfma_f32_16x16x32_bf16(
            a[mt], b[nt], acc[mt][nt], 0, 0, 0);
  }

  // ---- epilogue: logits = w*sim+b, fused LSE + diag ----
  float w = *wp, bb = *bp;
  float dsum = 0.f;
#pragma unroll
  for (int mt = 0; mt < 2; ++mt)
#pragma unroll
    for (int nt = 0; nt < 4; ++nt) {
      int c = wid * 64 + nt * 16 + n15;
      bool isdiag = (c == j);
#pragma unroll
      for (int rg = 0; rg < 4; ++rg) {
        float v = fmaf(w, acc[mt][nt][rg], bb);
        acc[mt][nt][rg] = v;
        if (isdiag) dsum += v;
      }
    }

#pragma unroll
  for (int mt = 0; mt < 2; ++mt)
#pragma unroll
    for (int rg = 0; rg < 4; ++rg) {
      float m = -INFINITY;
#pragma unroll
      for (int nt = 0; nt < 4; ++nt) m = fmaxf(m, acc[mt][nt][rg]);
#pragma unroll
      for (int off = 1; off < 16; off <<= 1) m = fmaxf(m, __shfl_xor(m, off, 64));
      float s = 0.f;
#pragma unroll
      for (int nt = 0; nt < 4; ++nt) s += __expf(acc[mt][nt][rg] - m);
#pragma unroll
      for (int off = 1; off < 16; off <<= 1) s += __shfl_xor(s, off, 64);
      if (n15 == 0) {
        int r = mt * 16 + quad * 4 + rg;
        red[wid][r][0] = m;
        red[wid][r][1] = s;
      }
    }
#pragma unroll
  for (int off = 32; off > 0; off >>= 1) dsum += __shfl_xor(dsum, off, 64);
  if (lane == 0) dred[wid] = dsum;
  __syncthreads();

  // combine 8 wave-partials per row; rows 0..31 on threads 0..31 (wave 0)
  if (t < 32) {
    float M = -INFINITY;
#pragma unroll
    for (int ww = 0; ww < 8; ++ww) M = fmaxf(M, red[ww][t][0]);
    float S = 0.f;
#pragma unroll
    for (int ww = 0; ww < 8; ++ww) S += red[ww][t][1] * __expf(red[ww][t][0] - M);
    float lse = M + __logf(S);
#pragma unroll
    for (int off = 16; off > 0; off >>= 1) lse += __shfl_xor(lse, off, 64);
    if (t == 0) {
      float d = dred[0] + dred[1] + dred[2] + dred[3] +
                dred[4] + dred[5] + dred[6] + dred[7];
      // agent-scope store: performed at the device coherence point, so the
      // last block (any XCD) reads it without L2 writeback/invalidate fences
      __hip_atomic_store(&partials[j], lse - d, __ATOMIC_RELAXED,
                         __HIP_MEMORY_SCOPE_AGENT);
      unsigned int old = __hip_atomic_fetch_add(cnt, 1u, __ATOMIC_ACQ_REL,
                                                __HIP_MEMORY_SCOPE_AGENT);
      lastflag = (old == N_SPK - 1);
    }
  }
  __syncthreads();

  // ---- last block reduces the 512 partials (same order as the old
  //      finalize_kernel -> bit-identical result) ----
  if (lastflag) {
    float v = __hip_atomic_load(&partials[t], __ATOMIC_RELAXED,
                                __HIP_MEMORY_SCOPE_AGENT);
#pragma unroll
    for (int off = 32; off > 0; off >>= 1) v += __shfl_xor(v, off, 64);
    __shared__ float fr[8];
    if ((t & 63) == 0) fr[t >> 6] = v;
    __syncthreads();
    if (t == 0) {
      float s = fr[0] + fr[1] + fr[2] + fr[3] + fr[4] + fr[5] + fr[6] + fr[7];
      out[0] = s * (1.f / (N_SPK * N_UTT));
    }
  }
}

extern "C" void kernel_launch(void* const* d_in, const int* in_sizes, int n_in,
                              void* d_out, int out_size, void* d_ws, size_t ws_size,
                              hipStream_t stream) {
  const float* emb = (const float*)d_in[0];
  const float* wp  = (const float*)d_in[1];
  const float* bp  = (const float*)d_in[2];
  float* out = (float*)d_out;
  unsigned short* cnk = (unsigned short*)d_ws;                        // 512 KB
  float* partials = (float*)((char*)d_ws + (size_t)CNK_ELEMS * 2);    // 2 KB
  unsigned int* cnt =
      (unsigned int*)((char*)d_ws + (size_t)CNK_ELEMS * 2 + N_SPK * 4);

  centroid_kernel<<<N_SPK, 256, 0, stream>>>(emb, cnk, cnt);
  ge2e_kernel<<<N_SPK, 512, 0, stream>>>(emb, cnk, wp, bp, partials, cnt, out);
}

// Round 3
// 99.061 us; speedup vs baseline: 1.9574x; 1.0460x over previous
//
#include <hip/hip_runtime.h>
#include <math.h>

#define N_SPK 512
#define N_UTT 32
#define DIM   512
#define EPSN  1e-8f

typedef __attribute__((ext_vector_type(8))) short  short8;  // 8 bf16 = 4 VGPR
typedef __attribute__((ext_vector_type(4))) float  f32x4;   // MFMA C/D

// fp32 -> bf16 round-to-nearest-even
__device__ inline unsigned short f2bf(float x) {
  unsigned int u = __builtin_bit_cast(unsigned int, x);
  unsigned int r = (u + 0x7fffu + ((u >> 16) & 1u)) >> 16;
  return (unsigned short)r;
}

// ws layout: [0, 512KB) = cnk (bf16, K-chunked); [512KB, +1KB) = partials
#define CNK_ELEMS (N_SPK * DIM)

// Kernel 1: centroid (mean over U) + L2-normalize (fp32) -> bf16, stored
// K-CHUNKED: cnk[(kc*N_SPK + c)*32 + (k&31)], kc = k/32 -> the GEMM's
// B-fragment loads land in a contiguous 1KB run per instruction.
__global__ __launch_bounds__(256) void centroid_kernel(
    const float* __restrict__ emb, unsigned short* __restrict__ cnk) {
  int j = blockIdx.x, t = threadIdx.x;
  int c4 = t & 127, half = t >> 7;  // c4: which float4 of the row (128/row)
  const float4* base = (const float4*)(emb + (size_t)j * N_UTT * DIM);
  float4 s = {0.f, 0.f, 0.f, 0.f};
#pragma unroll
  for (int u = 0; u < 16; ++u) {
    float4 v = base[(half + 2 * u) * 128 + c4];
    s.x += v.x; s.y += v.y; s.z += v.z; s.w += v.w;
  }
  __shared__ float4 comb[128];
  if (half) comb[c4] = s;
  __syncthreads();
  float4 m = {0.f, 0.f, 0.f, 0.f};
  float ss = 0.f;
  if (!half) {
    float4 o = comb[c4];
    m.x = (s.x + o.x) * (1.f / N_UTT);
    m.y = (s.y + o.y) * (1.f / N_UTT);
    m.z = (s.z + o.z) * (1.f / N_UTT);
    m.w = (s.w + o.w) * (1.f / N_UTT);
    ss = m.x * m.x + m.y * m.y + m.z * m.z + m.w * m.w;
  }
#pragma unroll
  for (int off = 32; off > 0; off >>= 1) ss += __shfl_xor(ss, off, 64);
  __shared__ float red[4];
  if ((t & 63) == 0) red[t >> 6] = ss;
  __syncthreads();
  float total = red[0] + red[1] + red[2] + red[3];
  float inv = 1.f / fmaxf(sqrtf(total), EPSN);
  if (!half) {
    int d0 = c4 * 4;          // first of this thread's 4 dims
    int kc = d0 >> 5;         // k-chunk
    unsigned short* p = cnk + ((size_t)kc * N_SPK + j) * 32 + (d0 & 31);
    p[0] = f2bf(m.x * inv); p[1] = f2bf(m.y * inv);
    p[2] = f2bf(m.z * inv); p[3] = f2bf(m.w * inv);
  }
}

// Kernel 2: block b owns speakers 2b, 2b+1 (M=64 rows) -> 256 blocks,
// 1024 threads (16 waves). Halves total B-operand L2 traffic vs the
// 1-speaker/block layout (268MB -> 134MB): each block streams cnk once.
// All fragment/epilogue mappings identical to the Round-1-verified fused
// kernel's phase 2 (absmax 0.0), run here as a plain standalone dispatch.
__global__ __launch_bounds__(1024) void ge2e_kernel(
    const float* __restrict__ emb, const unsigned short* __restrict__ cnk,
    const float* __restrict__ wp, const float* __restrict__ bp,
    float* __restrict__ partials) {
  __shared__ __align__(16) unsigned short E[64 * DIM];  // 64 KB
  __shared__ float red[16][64][2];                      // 8 KB (m, s)
  __shared__ float dred[16];

  int b = blockIdx.x;
  int t = threadIdx.x;
  int lane = t & 63, wid = t >> 6;
  int n15 = lane & 15, quad = lane >> 4;
  int sp = wid >> 3, ws8 = wid & 7;  // wave's speaker half + index within it
  int j = 2 * b + sp;

  // ---- stage + fp32 normalize + bf16 pack; wave owns 4 rows ----
#pragma unroll
  for (int r4 = 0; r4 < 4; ++r4) {
    int R = sp * 32 + ws8 * 4 + r4;  // block row 0..63
    const float* rp = emb + ((size_t)j * N_UTT + ws8 * 4 + r4) * DIM + lane * 8;
    float4 v0 = *(const float4*)rp;
    float4 v1 = *(const float4*)(rp + 4);
    float ss = v0.x * v0.x + v0.y * v0.y + v0.z * v0.z + v0.w * v0.w +
               v1.x * v1.x + v1.y * v1.y + v1.z * v1.z + v1.w * v1.w;
#pragma unroll
    for (int off = 32; off > 0; off >>= 1) ss += __shfl_xor(ss, off, 64);
    float inv = 1.f / fmaxf(sqrtf(ss), EPSN);
    short8 pk;
    pk[0] = (short)f2bf(v0.x * inv); pk[1] = (short)f2bf(v0.y * inv);
    pk[2] = (short)f2bf(v0.z * inv); pk[3] = (short)f2bf(v0.w * inv);
    pk[4] = (short)f2bf(v1.x * inv); pk[5] = (short)f2bf(v1.y * inv);
    pk[6] = (short)f2bf(v1.z * inv); pk[7] = (short)f2bf(v1.w * inv);
    int sw = lane ^ (R & 7);
    *(short8*)&E[R * DIM + sw * 8] = pk;
  }
  __syncthreads();

  // ---- MFMA GEMM: wave wid computes rows 0..63 x cols wid*32..+31 ----
  f32x4 acc[4][2];
#pragma unroll
  for (int mt = 0; mt < 4; ++mt)
#pragma unroll
    for (int nt = 0; nt < 2; ++nt) acc[mt][nt] = (f32x4){0.f, 0.f, 0.f, 0.f};

  for (int ks = 0; ks < 16; ++ks) {
    short8 bfr[2];
#pragma unroll
    for (int nt = 0; nt < 2; ++nt) {
      int c = wid * 32 + nt * 16 + n15;  // B[n][k]: lane=col, quad picks 8 k's
      bfr[nt] = *(const short8*)(cnk + ((size_t)ks * N_SPK + c) * 32 + quad * 8);
    }
    short8 afr[4];
#pragma unroll
    for (int mt = 0; mt < 4; ++mt) {
      int r = mt * 16 + n15;
      int sw = (ks * 4 + quad) ^ (r & 7);
      afr[mt] = *(const short8*)&E[r * DIM + sw * 8];
    }
#pragma unroll
    for (int mt = 0; mt < 4; ++mt)
#pragma unroll
      for (int nt = 0; nt < 2; ++nt)
        acc[mt][nt] = __builtin_amdgcn_mfma_f32_16x16x32_bf16(
            afr[mt], bfr[nt], acc[mt][nt], 0, 0, 0);
  }

  // ---- epilogue: logits = w*sim+b, fused LSE + diag ----
  float w = *wp, bb = *bp;
  float dsum = 0.f;
#pragma unroll
  for (int mt = 0; mt < 4; ++mt)
#pragma unroll
    for (int nt = 0; nt < 2; ++nt) {
      int c = wid * 32 + nt * 16 + n15;
      bool isdiag = (c == 2 * b + (mt >> 1));  // rows mt*16.. are speaker mt>>1
#pragma unroll
      for (int rg = 0; rg < 4; ++rg) {
        float v = fmaf(w, acc[mt][nt][rg], bb);
        acc[mt][nt][rg] = v;
        if (isdiag) dsum += v;
      }
    }

#pragma unroll
  for (int mt = 0; mt < 4; ++mt)
#pragma unroll
    for (int rg = 0; rg < 4; ++rg) {
      float m = fmaxf(acc[mt][0][rg], acc[mt][1][rg]);
#pragma unroll
      for (int off = 1; off < 16; off <<= 1) m = fmaxf(m, __shfl_xor(m, off, 64));
      float s = __expf(acc[mt][0][rg] - m) + __expf(acc[mt][1][rg] - m);
#pragma unroll
      for (int off = 1; off < 16; off <<= 1) s += __shfl_xor(s, off, 64);
      if (n15 == 0) {
        int r = mt * 16 + quad * 4 + rg;  // C/D: row = quad*4+reg within tile
        red[wid][r][0] = m;
        red[wid][r][1] = s;
      }
    }
#pragma unroll
  for (int off = 32; off > 0; off >>= 1) dsum += __shfl_xor(dsum, off, 64);
  if (lane == 0) dred[wid] = dsum;
  __syncthreads();

  if (t < 64) {  // wave 0 combines 16 wave-partials for its row t
    float M = -INFINITY;
#pragma unroll
    for (int ww = 0; ww < 16; ++ww) M = fmaxf(M, red[ww][t][0]);
    float S = 0.f;
#pragma unroll
    for (int ww = 0; ww < 16; ++ww) S += red[ww][t][1] * __expf(red[ww][t][0] - M);
    float lse = M + __logf(S);
#pragma unroll
    for (int off = 32; off > 0; off >>= 1) lse += __shfl_xor(lse, off, 64);
    if (t == 0) {
      float d = 0.f;
#pragma unroll
      for (int ww = 0; ww < 16; ++ww) d += dred[ww];
      partials[b] = lse - d;  // one plain store; no atomics
    }
  }
}

// Kernel 3: reduce the 256 per-block partials -> the loss scalar.
__global__ __launch_bounds__(256) void finalize_kernel(
    const float* __restrict__ partials, float* __restrict__ out) {
  int t = threadIdx.x;
  float v = partials[t];
#pragma unroll
  for (int off = 32; off > 0; off >>= 1) v += __shfl_xor(v, off, 64);
  __shared__ float r[4];
  if ((t & 63) == 0) r[t >> 6] = v;
  __syncthreads();
  if (t == 0) {
    float s = r[0] + r[1] + r[2] + r[3];
    out[0] = s * (1.f / (N_SPK * N_UTT));
  }
}

extern "C" void kernel_launch(void* const* d_in, const int* in_sizes, int n_in,
                              void* d_out, int out_size, void* d_ws, size_t ws_size,
                              hipStream_t stream) {
  const float* emb = (const float*)d_in[0];
  const float* wp  = (const float*)d_in[1];
  const float* bp  = (const float*)d_in[2];
  float* out = (float*)d_out;
  unsigned short* cnk = (unsigned short*)d_ws;                      // 512 KB
  float* partials = (float*)((char*)d_ws + (size_t)CNK_ELEMS * 2);  // 1 KB

  centroid_kernel<<<N_SPK, 256, 0, stream>>>(emb, cnk);
  ge2e_kernel<<<256, 1024, 0, stream>>>(emb, cnk, wp, bp, partials);
  finalize_kernel<<<1, 256, 0, stream>>>(partials, out);
}